// Round 1
// baseline (183.437 us; speedup 1.0000x reference)
//
#include <hip/hip_runtime.h>
#include <hip/hip_bf16.h>
#include <math.h>

#define NB 8
#define LL 8192
#define DD 64
#define NS 11
#define NR 4
#define NC 128        // chunks
#define LC (LL/NC)    // 64 positions per chunk
#define CONV_LT 128
#define KW 63

__device__ __forceinline__ float sigmoidf_(float v){ return 1.f/(1.f+__expf(-v)); }

// ---------------- K1: depthwise conv (k=63, pad 31) + BN partial sums ----------------
__global__ __launch_bounds__(256) void k_conv(const float* __restrict__ x,
                                              const float* __restrict__ w,
                                              float* __restrict__ xc,
                                              float* __restrict__ bn_acc){
  const int b  = blockIdx.x / (LL/CONV_LT);
  const int lt = blockIdx.x % (LL/CONV_LT);
  const int l0 = lt*CONV_LT;
  __shared__ float xt[(CONV_LT+62)*DD];
  __shared__ float rs[256], rq[256];
  const int t = threadIdx.x;
  for (int i=t; i<(CONV_LT+62)*DD; i+=256){
    int lrel = i/DD, d = i%DD;
    int lg = l0 - 31 + lrel;
    xt[i] = (lg>=0 && lg<LL) ? x[((size_t)b*LL+lg)*DD + d] : 0.f;
  }
  __syncthreads();
  const int d = t & 63;
  const int lq = t >> 6;
  float wr[KW];
  #pragma unroll
  for (int k=0;k<KW;k++) wr[k] = w[d*KW+k];
  float lsum=0.f, lsq=0.f;
  for (int g=0; g<CONV_LT/16; ++g){
    int lrb = g*16 + lq*4;
    float acc[4] = {0.f,0.f,0.f,0.f};
    #pragma unroll
    for (int k=0;k<KW+3;k++){
      float xv = xt[(lrb+k)*DD + d];
      #pragma unroll
      for (int j=0;j<4;j++){
        int kk = k - j;
        if (kk>=0 && kk<KW) acc[j] = fmaf(wr[kk], xv, acc[j]);
      }
    }
    #pragma unroll
    for (int j=0;j<4;j++){
      int l = l0 + lrb + j;
      xc[((size_t)b*LL+l)*DD + d] = acc[j];
      lsum += acc[j]; lsq = fmaf(acc[j],acc[j],lsq);
    }
  }
  rs[t]=lsum; rq[t]=lsq;
  __syncthreads();
  if (t<64){
    float s = rs[t]+rs[t+64]+rs[t+128]+rs[t+192];
    float q = rq[t]+rq[t+64]+rq[t+128]+rq[t+192];
    atomicAdd(&bn_acc[t],    s);
    atomicAdd(&bn_acc[64+t], q);
  }
}

// ---------------- K2: finalize BN params ----------------
__global__ void k_bn(const float* __restrict__ acc, const float* __restrict__ gamma,
                     const float* __restrict__ beta, float* __restrict__ bnp){
  int d = threadIdx.x;
  const float inv_n = 1.f/((float)NB*(float)LL);
  float mean = acc[d]*inv_n;
  float var  = acc[64+d]*inv_n - mean*mean;
  float sc = gamma[d] * rsqrtf(var + 1e-5f);
  bnp[d]    = sc;
  bnp[64+d] = beta[d] - mean*sc;
}

// ---------------- K3: BN+SiLU -> u ; x_proj (26x64) ; dt proj (64x4) + softplus -> delta
// delta written into the xc buffer (exact same footprint per block; safe in-place)
__global__ __launch_bounds__(256) void k_proj(float* __restrict__ xc_delta,
                                              const float* __restrict__ bnp,
                                              const float* __restrict__ xpw,
                                              const float* __restrict__ dtw,
                                              const float* __restrict__ dtb,
                                              float* __restrict__ u,
                                              float* __restrict__ bc){
  const int b  = blockIdx.x / (LL/64);
  const int lt = blockIdx.x % (LL/64);
  const int l0 = lt*64;
  __shared__ float ul[64*64];
  __shared__ float wsh_t[DD*26];     // transposed: [dd][c]
  __shared__ float xd[64*NR];        // dts per position
  __shared__ float dtwsh[DD*NR];
  const int t = threadIdx.x;
  for (int i=t; i<26*64; i+=256){ int c=i/64, dd=i%64; wsh_t[dd*26+c] = xpw[i]; }
  for (int i=t; i<DD*NR; i+=256)  dtwsh[i] = dtw[i];
  const int d = t & 63, lq = t >> 6;
  float sc = bnp[d], sh = bnp[64+d];
  for (int lr=lq; lr<64; lr+=4){
    float v = xc_delta[((size_t)b*LL + l0+lr)*DD + d];
    v = fmaf(v, sc, sh);
    float uu = v * sigmoidf_(v);
    ul[lr*64+d] = uu;
    u[((size_t)b*LL + l0+lr)*DD + d] = uu;
  }
  __syncthreads();
  for (int ii=t; ii<32*64; ii+=256){
    int c = ii & 31, lr = ii >> 5;
    if (c < 26){
      float s=0.f;
      #pragma unroll 16
      for (int dd=0; dd<64; dd++) s = fmaf(wsh_t[dd*26+c], ul[lr*64+dd], s);
      if (c < NR) xd[lr*NR+c] = s;
      else {
        int pos = c - NR;                       // 0..21 ; B:0..10  C:11..21
        int slot = (pos < NS) ? pos : pos+1;    // pad slots 11 and 23
        bc[((size_t)b*LL + l0+lr)*24 + slot] = s;
      }
    }
  }
  __syncthreads();
  float bias = dtb[d];
  for (int lr=lq; lr<64; lr+=4){
    float s = bias;
    #pragma unroll
    for (int r=0;r<NR;r++) s = fmaf(dtwsh[d*NR+r], xd[lr*NR+r], s);
    float sp = fmaxf(s,0.f) + log1pf(expf(-fabsf(s)));   // stable softplus
    xc_delta[((size_t)b*LL + l0+lr)*DD + d] = sp;
  }
}

// ---------------- K4: chunk-local scan (h0 = 0), record h_end and delta-sum --------
__global__ __launch_bounds__(256) void k_scanA(const float* __restrict__ delta,
                                               const float* __restrict__ u,
                                               const float* __restrict__ bc,
                                               const float* __restrict__ Alog,
                                               float* __restrict__ chunkst){
  const int task = blockIdx.x*4 + (threadIdx.x>>6);
  const int d = threadIdx.x & 63;
  const int b = task / NC, c = task % NC;
  float a[NS];
  #pragma unroll
  for (int n=0;n<NS;n++) a[n] = -expf(Alog[d*NS+n]);
  float h[NS];
  #pragma unroll
  for (int n=0;n<NS;n++) h[n]=0.f;
  float dsum=0.f;
  const int l0 = c*LC;
  for (int l=l0; l<l0+LC; ++l){
    size_t p = (size_t)b*LL + l;
    float de = delta[p*DD+d];
    float uu = u[p*DD+d];
    float du = de*uu;
    dsum += de;
    float bca[12];
    const float4* q = reinterpret_cast<const float4*>(bc + p*24);
    *reinterpret_cast<float4*>(&bca[0]) = q[0];
    *reinterpret_cast<float4*>(&bca[4]) = q[1];
    *reinterpret_cast<float4*>(&bca[8]) = q[2];
    #pragma unroll
    for (int n=0;n<NS;n++){
      float dA = __expf(a[n]*de);
      h[n] = fmaf(dA, h[n], du*bca[n]);
    }
  }
  size_t o = ((size_t)task*64 + d)*12;
  #pragma unroll
  for (int n=0;n<NS;n++) chunkst[o+n]=h[n];
  chunkst[o+NS]=dsum;
}

// ---------------- K5: serial cross-chunk propagation ----------------
__global__ void k_scanMid(const float* __restrict__ chunkst,
                          const float* __restrict__ Alog,
                          float* __restrict__ hin){
  int tid = blockIdx.x*256 + threadIdx.x;
  if (tid >= NB*DD*NS) return;
  int n = tid % NS; int d = (tid/NS) % DD; int b = tid/(NS*DD);
  float a = -expf(Alog[d*NS+n]);
  float h = 0.f;
  #pragma unroll 4
  for (int c=0;c<NC;c++){
    size_t o = (((size_t)(b*NC+c))*64 + d)*12;
    float hend = chunkst[o+n];
    float ds   = chunkst[o+NS];
    hin[(((size_t)(b*NC+c))*64 + d)*NS + n] = h;
    h = fmaf(__expf(a*ds), h, hend);
  }
}

// ---------------- K6: replay scan with h_in, y, RMSNorm over D, SiLU gating -------
__global__ __launch_bounds__(256) void k_scanB(const float* __restrict__ delta,
                                               const float* __restrict__ u,
                                               const float* __restrict__ bc,
                                               const float* __restrict__ Alog,
                                               const float* __restrict__ hin,
                                               const float* __restrict__ Dsv,
                                               const float* __restrict__ rmss,
                                               const float* __restrict__ x,
                                               float* __restrict__ out){
  const int task = blockIdx.x*4 + (threadIdx.x>>6);
  const int d = threadIdx.x & 63;
  const int b = task / NC, c = task % NC;
  float a[NS], h[NS];
  #pragma unroll
  for (int n=0;n<NS;n++) a[n] = -expf(Alog[d*NS+n]);
  size_t ho = ((size_t)task*64 + d)*NS;
  #pragma unroll
  for (int n=0;n<NS;n++) h[n] = hin[ho+n];
  const float Dd = Dsv[d];
  const float rsc = rmss[d];
  const int l0 = c*LC;
  for (int l=l0; l<l0+LC; ++l){
    size_t p = (size_t)b*LL + l;
    float de = delta[p*DD+d];
    float uu = u[p*DD+d];
    float du = de*uu;
    float bca[24];
    const float4* q = reinterpret_cast<const float4*>(bc + p*24);
    *reinterpret_cast<float4*>(&bca[0])  = q[0];
    *reinterpret_cast<float4*>(&bca[4])  = q[1];
    *reinterpret_cast<float4*>(&bca[8])  = q[2];
    *reinterpret_cast<float4*>(&bca[12]) = q[3];
    *reinterpret_cast<float4*>(&bca[16]) = q[4];
    *reinterpret_cast<float4*>(&bca[20]) = q[5];
    float y = Dd*uu;
    #pragma unroll
    for (int n=0;n<NS;n++){
      float dA = __expf(a[n]*de);
      h[n] = fmaf(dA, h[n], du*bca[n]);
      y = fmaf(h[n], bca[12+n], y);
    }
    float ss = y*y;
    #pragma unroll
    for (int m=1;m<64;m<<=1) ss += __shfl_xor(ss, m, 64);
    float yn = rsc * rsqrtf(ss*(1.f/64.f) + 1e-5f) * y;
    float z = x[p*DD+d];
    out[p*DD+d] = yn * (z * sigmoidf_(z));
  }
}

extern "C" void kernel_launch(void* const* d_in, const int* in_sizes, int n_in,
                              void* d_out, int out_size, void* d_ws, size_t ws_size,
                              hipStream_t stream) {
  const float* x     = (const float*)d_in[0];
  const float* w     = (const float*)d_in[1];
  const float* gamma = (const float*)d_in[2];
  const float* beta  = (const float*)d_in[3];
  const float* xpw   = (const float*)d_in[4];
  const float* dtw   = (const float*)d_in[5];
  const float* dtb   = (const float*)d_in[6];
  const float* Alog  = (const float*)d_in[7];
  const float* Dsv   = (const float*)d_in[8];
  const float* rmss  = (const float*)d_in[9];
  float* out = (float*)d_out;

  float* f = (float*)d_ws;
  const size_t n_xld = (size_t)NB*LL*DD;       // 4,194,304
  float* xc      = f;                          // conv out, later overwritten by delta
  float* u       = xc + n_xld;
  float* bc      = u  + n_xld;                 // (b,l,24): B[0..10],pad,C[0..10],pad
  float* chunkst = bc + (size_t)NB*LL*24;      // (b,c,d,12)
  float* hin     = chunkst + (size_t)NB*NC*64*12;  // (b,c,d,11)
  float* bn_acc  = hin + (size_t)NB*NC*64*NS;
  float* bnp     = bn_acc + 128;

  hipMemsetAsync(bn_acc, 0, 128*sizeof(float), stream);
  k_conv   <<<NB*(LL/CONV_LT), 256, 0, stream>>>(x, w, xc, bn_acc);
  k_bn     <<<1, 64, 0, stream>>>(bn_acc, gamma, beta, bnp);
  k_proj   <<<NB*(LL/64), 256, 0, stream>>>(xc, bnp, xpw, dtw, dtb, u, bc);
  k_scanA  <<<(NB*NC)/4, 256, 0, stream>>>(xc, u, bc, Alog, chunkst);
  k_scanMid<<<(NB*DD*NS+255)/256, 256, 0, stream>>>(chunkst, Alog, hin);
  k_scanB  <<<(NB*NC)/4, 256, 0, stream>>>(xc, u, bc, Alog, hin, Dsv, rmss, x, out);
}

// Round 2
// 176.819 us; speedup vs baseline: 1.0374x; 1.0374x over previous
//
#include <hip/hip_runtime.h>
#include <hip/hip_bf16.h>
#include <math.h>

#define NB 8
#define LL 8192
#define DD 64
#define NS 11
#define NR 4
#define NC 512        // chunks
#define LC (LL/NC)    // 16 positions per chunk
#define CONV_LT 128
#define KW 63

__device__ __forceinline__ float sigmoidf_(float v){ return 1.f/(1.f+__expf(-v)); }

// ---------------- K1: depthwise conv (k=63, pad 31) + BN partial sums ----------------
__global__ __launch_bounds__(256) void k_conv(const float* __restrict__ x,
                                              const float* __restrict__ w,
                                              float* __restrict__ xc,
                                              float* __restrict__ bn_acc){
  const int b  = blockIdx.x / (LL/CONV_LT);
  const int lt = blockIdx.x % (LL/CONV_LT);
  const int l0 = lt*CONV_LT;
  __shared__ float xt[(CONV_LT+62)*DD];
  __shared__ float rs[256], rq[256];
  const int t = threadIdx.x;
  for (int i=t; i<(CONV_LT+62)*DD; i+=256){
    int lrel = i/DD, d = i%DD;
    int lg = l0 - 31 + lrel;
    xt[i] = (lg>=0 && lg<LL) ? x[((size_t)b*LL+lg)*DD + d] : 0.f;
  }
  __syncthreads();
  const int d = t & 63;
  const int lq = t >> 6;
  float wr[KW];
  #pragma unroll
  for (int k=0;k<KW;k++) wr[k] = w[d*KW+k];
  float lsum=0.f, lsq=0.f;
  for (int g=0; g<CONV_LT/16; ++g){
    int lrb = g*16 + lq*4;
    float acc[4] = {0.f,0.f,0.f,0.f};
    #pragma unroll
    for (int k=0;k<KW+3;k++){
      float xv = xt[(lrb+k)*DD + d];
      #pragma unroll
      for (int j=0;j<4;j++){
        int kk = k - j;
        if (kk>=0 && kk<KW) acc[j] = fmaf(wr[kk], xv, acc[j]);
      }
    }
    #pragma unroll
    for (int j=0;j<4;j++){
      int l = l0 + lrb + j;
      xc[((size_t)b*LL+l)*DD + d] = acc[j];
      lsum += acc[j]; lsq = fmaf(acc[j],acc[j],lsq);
    }
  }
  rs[t]=lsum; rq[t]=lsq;
  __syncthreads();
  if (t<64){
    float s = rs[t]+rs[t+64]+rs[t+128]+rs[t+192];
    float q = rq[t]+rq[t+64]+rq[t+128]+rq[t+192];
    atomicAdd(&bn_acc[t],    s);
    atomicAdd(&bn_acc[64+t], q);
  }
}

// ---------------- K2: BN-finalize (per-block, fused) + SiLU -> u ; x_proj ; dt proj ----
__global__ __launch_bounds__(256) void k_proj(float* __restrict__ xc_delta,
                                              const float* __restrict__ bn_acc,
                                              const float* __restrict__ gamma,
                                              const float* __restrict__ beta,
                                              const float* __restrict__ xpw,
                                              const float* __restrict__ dtw,
                                              const float* __restrict__ dtb,
                                              float* __restrict__ u,
                                              float* __restrict__ bc){
  const int b  = blockIdx.x / (LL/64);
  const int lt = blockIdx.x % (LL/64);
  const int l0 = lt*64;
  __shared__ float ul[64*64];
  __shared__ float wsh_t[DD*26];     // transposed: [dd][c]
  __shared__ float xd[64*NR];        // dts per position
  __shared__ float dtwsh[DD*NR];
  const int t = threadIdx.x;
  for (int i=t; i<26*64; i+=256){ int c=i/64, dd=i%64; wsh_t[dd*26+c] = xpw[i]; }
  for (int i=t; i<DD*NR; i+=256)  dtwsh[i] = dtw[i];
  const int d = t & 63, lq = t >> 6;
  const float inv_n = 1.f/((float)NB*(float)LL);
  float mean = bn_acc[d]*inv_n;
  float var  = bn_acc[64+d]*inv_n - mean*mean;
  float sc = gamma[d] * rsqrtf(var + 1e-5f);
  float sh = beta[d] - mean*sc;
  for (int lr=lq; lr<64; lr+=4){
    float v = xc_delta[((size_t)b*LL + l0+lr)*DD + d];
    v = fmaf(v, sc, sh);
    float uu = v * sigmoidf_(v);
    ul[lr*64+d] = uu;
    u[((size_t)b*LL + l0+lr)*DD + d] = uu;
  }
  __syncthreads();
  for (int ii=t; ii<32*64; ii+=256){
    int c = ii & 31, lr = ii >> 5;
    if (c < 26){
      float s=0.f;
      #pragma unroll 16
      for (int dd=0; dd<64; dd++) s = fmaf(wsh_t[dd*26+c], ul[lr*64+dd], s);
      if (c < NR) xd[lr*NR+c] = s;
      else {
        int pos = c - NR;                       // 0..21 ; B:0..10  C:11..21
        int slot = (pos < NS) ? pos : pos+1;    // pad slots 11 and 23
        bc[((size_t)b*LL + l0+lr)*24 + slot] = s;
      }
    }
  }
  __syncthreads();
  float bias = dtb[d];
  for (int lr=lq; lr<64; lr+=4){
    float s = bias;
    #pragma unroll
    for (int r=0;r<NR;r++) s = fmaf(dtwsh[d*NR+r], xd[lr*NR+r], s);
    float sp = fmaxf(s,0.f) + log1pf(expf(-fabsf(s)));   // stable softplus
    xc_delta[((size_t)b*LL + l0+lr)*DD + d] = sp;
  }
}

// ---------------- K3: chunk-local scan (h0 = 0), record h_end and delta-sum --------
__global__ __launch_bounds__(256,4) void k_scanA(const float* __restrict__ delta,
                                               const float* __restrict__ u,
                                               const float* __restrict__ bc,
                                               const float* __restrict__ Alog,
                                               float* __restrict__ chunkst){
  const int task = blockIdx.x*4 + (threadIdx.x>>6);
  const int d = threadIdx.x & 63;
  const int b = task / NC, c = task % NC;
  float a[NS];
  #pragma unroll
  for (int n=0;n<NS;n++) a[n] = -expf(Alog[d*NS+n]);
  float h[NS];
  #pragma unroll
  for (int n=0;n<NS;n++) h[n]=0.f;
  float dsum=0.f;
  const int l0 = c*LC;
  #pragma unroll 4
  for (int l=l0; l<l0+LC; ++l){
    size_t p = (size_t)b*LL + l;
    float de = delta[p*DD+d];
    float uu = u[p*DD+d];
    float du = de*uu;
    dsum += de;
    float bca[12];
    const float4* q = reinterpret_cast<const float4*>(bc + p*24);
    *reinterpret_cast<float4*>(&bca[0]) = q[0];
    *reinterpret_cast<float4*>(&bca[4]) = q[1];
    *reinterpret_cast<float4*>(&bca[8]) = q[2];
    #pragma unroll
    for (int n=0;n<NS;n++){
      float dA = __expf(a[n]*de);
      h[n] = fmaf(dA, h[n], du*bca[n]);
    }
  }
  size_t o = ((size_t)task*64 + d)*12;
  #pragma unroll
  for (int n=0;n<NS;n++) chunkst[o+n]=h[n];
  chunkst[o+NS]=dsum;
}

// ---------------- K4: serial cross-chunk propagation (exp off the chain) ----------
__global__ void k_scanMid(const float* __restrict__ chunkst,
                          const float* __restrict__ Alog,
                          float* __restrict__ hin){
  int tid = blockIdx.x*256 + threadIdx.x;
  if (tid >= NB*DD*NS) return;
  int n = tid % NS; int d = (tid/NS) % DD; int b = tid/(NS*DD);
  float a = -expf(Alog[d*NS+n]);
  float h = 0.f;
  for (int c0=0; c0<NC; c0+=8){
    float hend[8], dA[8];
    #pragma unroll
    for (int j=0;j<8;j++){
      size_t o = (((size_t)(b*NC+c0+j))*64 + d)*12;
      hend[j] = chunkst[o+n];
      dA[j]   = __expf(a*chunkst[o+NS]);
    }
    #pragma unroll
    for (int j=0;j<8;j++){
      hin[(((size_t)(b*NC+c0+j))*64 + d)*NS + n] = h;
      h = fmaf(dA[j], h, hend[j]);
    }
  }
}

// ---------------- K5: replay scan with h_in, y, RMSNorm over D, SiLU gating -------
__global__ __launch_bounds__(256,4) void k_scanB(const float* __restrict__ delta,
                                               const float* __restrict__ u,
                                               const float* __restrict__ bc,
                                               const float* __restrict__ Alog,
                                               const float* __restrict__ hin,
                                               const float* __restrict__ Dsv,
                                               const float* __restrict__ rmss,
                                               const float* __restrict__ x,
                                               float* __restrict__ out){
  const int task = blockIdx.x*4 + (threadIdx.x>>6);
  const int d = threadIdx.x & 63;
  const int b = task / NC, c = task % NC;
  float a[NS], h[NS];
  #pragma unroll
  for (int n=0;n<NS;n++) a[n] = -expf(Alog[d*NS+n]);
  size_t ho = ((size_t)task*64 + d)*NS;
  #pragma unroll
  for (int n=0;n<NS;n++) h[n] = hin[ho+n];
  const float Dd = Dsv[d];
  const float rsc = rmss[d];
  const int l0 = c*LC;
  #pragma unroll 2
  for (int l=l0; l<l0+LC; ++l){
    size_t p = (size_t)b*LL + l;
    float de = delta[p*DD+d];
    float uu = u[p*DD+d];
    float du = de*uu;
    float bca[24];
    const float4* q = reinterpret_cast<const float4*>(bc + p*24);
    *reinterpret_cast<float4*>(&bca[0])  = q[0];
    *reinterpret_cast<float4*>(&bca[4])  = q[1];
    *reinterpret_cast<float4*>(&bca[8])  = q[2];
    *reinterpret_cast<float4*>(&bca[12]) = q[3];
    *reinterpret_cast<float4*>(&bca[16]) = q[4];
    *reinterpret_cast<float4*>(&bca[20]) = q[5];
    float y = Dd*uu;
    #pragma unroll
    for (int n=0;n<NS;n++){
      float dA = __expf(a[n]*de);
      h[n] = fmaf(dA, h[n], du*bca[n]);
      y = fmaf(h[n], bca[12+n], y);
    }
    float ss = y*y;
    #pragma unroll
    for (int m=1;m<64;m<<=1) ss += __shfl_xor(ss, m, 64);
    float yn = rsc * rsqrtf(ss*(1.f/64.f) + 1e-5f) * y;
    float z = x[p*DD+d];
    out[p*DD+d] = yn * (z * sigmoidf_(z));
  }
}

extern "C" void kernel_launch(void* const* d_in, const int* in_sizes, int n_in,
                              void* d_out, int out_size, void* d_ws, size_t ws_size,
                              hipStream_t stream) {
  const float* x     = (const float*)d_in[0];
  const float* w     = (const float*)d_in[1];
  const float* gamma = (const float*)d_in[2];
  const float* beta  = (const float*)d_in[3];
  const float* xpw   = (const float*)d_in[4];
  const float* dtw   = (const float*)d_in[5];
  const float* dtb   = (const float*)d_in[6];
  const float* Alog  = (const float*)d_in[7];
  const float* Dsv   = (const float*)d_in[8];
  const float* rmss  = (const float*)d_in[9];
  float* out = (float*)d_out;

  float* f = (float*)d_ws;
  const size_t n_xld = (size_t)NB*LL*DD;       // 4,194,304
  float* xc      = f;                          // conv out, later overwritten by delta
  float* u       = xc + n_xld;
  float* bc      = u  + n_xld;                 // (b,l,24): B[0..10],pad,C[0..10],pad
  float* chunkst = bc + (size_t)NB*LL*24;      // (b,c,d,12)
  float* hin     = chunkst + (size_t)NB*NC*64*12;  // (b,c,d,11)
  float* bn_acc  = hin + (size_t)NB*NC*64*NS;

  hipMemsetAsync(bn_acc, 0, 128*sizeof(float), stream);
  k_conv   <<<NB*(LL/CONV_LT), 256, 0, stream>>>(x, w, xc, bn_acc);
  k_proj   <<<NB*(LL/64), 256, 0, stream>>>(xc, bn_acc, gamma, beta, xpw, dtw, dtb, u, bc);
  k_scanA  <<<(NB*NC)/4, 256, 0, stream>>>(xc, u, bc, Alog, chunkst);
  k_scanMid<<<(NB*DD*NS+255)/256, 256, 0, stream>>>(chunkst, Alog, hin);
  k_scanB  <<<(NB*NC)/4, 256, 0, stream>>>(xc, u, bc, Alog, hin, Dsv, rmss, x, out);
}

// Round 3
// 160.406 us; speedup vs baseline: 1.1436x; 1.1023x over previous
//
#include <hip/hip_runtime.h>
#include <hip/hip_bf16.h>
#include <math.h>

#define NB 8
#define LL 8192
#define DD 64
#define NS 11
#define NR 4
#define NC 512        // chunks
#define LC (LL/NC)    // 16 positions per chunk
#define CONV_LT 128
#define KW 63

__device__ __forceinline__ float sigmoidf_(float v){ return 1.f/(1.f+__expf(-v)); }

// ---------------- K1: depthwise conv (k=63, pad 31) + BN partial sums ----------------
__global__ __launch_bounds__(256) void k_conv(const float* __restrict__ x,
                                              const float* __restrict__ w,
                                              float* __restrict__ xc,
                                              float* __restrict__ bn_acc){
  const int b  = blockIdx.x / (LL/CONV_LT);
  const int lt = blockIdx.x % (LL/CONV_LT);
  const int l0 = lt*CONV_LT;
  __shared__ float xt[(CONV_LT+62)*DD];
  __shared__ float rs[256], rq[256];
  const int t = threadIdx.x;
  for (int i=t; i<(CONV_LT+62)*DD; i+=256){
    int lrel = i/DD, d = i%DD;
    int lg = l0 - 31 + lrel;
    xt[i] = (lg>=0 && lg<LL) ? x[((size_t)b*LL+lg)*DD + d] : 0.f;
  }
  __syncthreads();
  const int d = t & 63;
  const int lq = t >> 6;
  float wr[KW];
  #pragma unroll
  for (int k=0;k<KW;k++) wr[k] = w[d*KW+k];
  float lsum=0.f, lsq=0.f;
  for (int g=0; g<CONV_LT/16; ++g){
    int lrb = g*16 + lq*4;
    float acc[4] = {0.f,0.f,0.f,0.f};
    #pragma unroll
    for (int k=0;k<KW+3;k++){
      float xv = xt[(lrb+k)*DD + d];
      #pragma unroll
      for (int j=0;j<4;j++){
        int kk = k - j;
        if (kk>=0 && kk<KW) acc[j] = fmaf(wr[kk], xv, acc[j]);
      }
    }
    #pragma unroll
    for (int j=0;j<4;j++){
      int l = l0 + lrb + j;
      xc[((size_t)b*LL+l)*DD + d] = acc[j];
      lsum += acc[j]; lsq = fmaf(acc[j],acc[j],lsq);
    }
  }
  rs[t]=lsum; rq[t]=lsq;
  __syncthreads();
  if (t<64){
    float s = rs[t]+rs[t+64]+rs[t+128]+rs[t+192];
    float q = rq[t]+rq[t+64]+rq[t+128]+rq[t+192];
    atomicAdd(&bn_acc[t],    s);
    atomicAdd(&bn_acc[64+t], q);
  }
}

// ---------------- K2: BN-finalize (per-block, fused) + SiLU -> u ; x_proj ; dt proj ----
__global__ __launch_bounds__(256) void k_proj(float* __restrict__ xc_delta,
                                              const float* __restrict__ bn_acc,
                                              const float* __restrict__ gamma,
                                              const float* __restrict__ beta,
                                              const float* __restrict__ xpw,
                                              const float* __restrict__ dtw,
                                              const float* __restrict__ dtb,
                                              float* __restrict__ u,
                                              float* __restrict__ bc){
  const int b  = blockIdx.x / (LL/64);
  const int lt = blockIdx.x % (LL/64);
  const int l0 = lt*64;
  __shared__ float ul[64*64];
  __shared__ float wsh_t[DD*26];     // transposed: [dd][c]
  __shared__ float xd[64*NR];        // dts per position
  __shared__ float dtwsh[DD*NR];
  const int t = threadIdx.x;
  for (int i=t; i<26*64; i+=256){ int c=i/64, dd=i%64; wsh_t[dd*26+c] = xpw[i]; }
  for (int i=t; i<DD*NR; i+=256)  dtwsh[i] = dtw[i];
  const int d = t & 63, lq = t >> 6;
  const float inv_n = 1.f/((float)NB*(float)LL);
  float mean = bn_acc[d]*inv_n;
  float var  = bn_acc[64+d]*inv_n - mean*mean;
  float sc = gamma[d] * rsqrtf(var + 1e-5f);
  float sh = beta[d] - mean*sc;
  for (int lr=lq; lr<64; lr+=4){
    float v = xc_delta[((size_t)b*LL + l0+lr)*DD + d];
    v = fmaf(v, sc, sh);
    float uu = v * sigmoidf_(v);
    ul[lr*64+d] = uu;
    u[((size_t)b*LL + l0+lr)*DD + d] = uu;
  }
  __syncthreads();
  for (int ii=t; ii<32*64; ii+=256){
    int c = ii & 31, lr = ii >> 5;
    if (c < 26){
      float s=0.f;
      #pragma unroll 16
      for (int dd=0; dd<64; dd++) s = fmaf(wsh_t[dd*26+c], ul[lr*64+dd], s);
      if (c < NR) xd[lr*NR+c] = s;
      else {
        int pos = c - NR;                       // 0..21 ; B:0..10  C:11..21
        int slot = (pos < NS) ? pos : pos+1;    // pad slots 11 and 23
        bc[((size_t)b*LL + l0+lr)*24 + slot] = s;
      }
    }
  }
  __syncthreads();
  float bias = dtb[d];
  for (int lr=lq; lr<64; lr+=4){
    float s = bias;
    #pragma unroll
    for (int r=0;r<NR;r++) s = fmaf(dtwsh[d*NR+r], xd[lr*NR+r], s);
    float sp = fmaxf(s,0.f) + log1pf(expf(-fabsf(s)));   // stable softplus
    xc_delta[((size_t)b*LL + l0+lr)*DD + d] = sp;
  }
}

// ---------------- K3: chunk-local scan (h0 = 0), record h_end and delta-sum --------
__global__ __launch_bounds__(256,4) void k_scanA(const float* __restrict__ delta,
                                               const float* __restrict__ u,
                                               const float* __restrict__ bc,
                                               const float* __restrict__ Alog,
                                               float* __restrict__ chunkst){
  const int task = blockIdx.x*4 + (threadIdx.x>>6);
  const int d = threadIdx.x & 63;
  const int b = task / NC, c = task % NC;
  float a[NS];
  #pragma unroll
  for (int n=0;n<NS;n++) a[n] = -expf(Alog[d*NS+n]);
  float h[NS];
  #pragma unroll
  for (int n=0;n<NS;n++) h[n]=0.f;
  float dsum=0.f;
  const int l0 = c*LC;
  #pragma unroll 4
  for (int l=l0; l<l0+LC; ++l){
    size_t p = (size_t)b*LL + l;
    float de = delta[p*DD+d];
    float uu = u[p*DD+d];
    float du = de*uu;
    dsum += de;
    float bca[12];
    const float4* q = reinterpret_cast<const float4*>(bc + p*24);
    *reinterpret_cast<float4*>(&bca[0]) = q[0];
    *reinterpret_cast<float4*>(&bca[4]) = q[1];
    *reinterpret_cast<float4*>(&bca[8]) = q[2];
    #pragma unroll
    for (int n=0;n<NS;n++){
      float dA = __expf(a[n]*de);
      h[n] = fmaf(dA, h[n], du*bca[n]);
    }
  }
  size_t o = ((size_t)task*64 + d)*12;
  #pragma unroll
  for (int n=0;n<NS;n++) chunkst[o+n]=h[n];
  chunkst[o+NS]=dsum;
}

// ---------------- K4: cross-chunk propagation — wave-parallel affine scan ----------
// one 64-lane wave per recurrence (b,d,n); lane j owns chunks [8j, 8j+8)
__global__ __launch_bounds__(256) void k_scanMid(const float* __restrict__ chunkst,
                                                 const float* __restrict__ Alog,
                                                 float* __restrict__ hin){
  const int rec  = blockIdx.x*4 + (threadIdx.x>>6);   // 0..5631
  const int lane = threadIdx.x & 63;
  const int n  = rec % NS;
  const int d  = (rec/NS) % DD;
  const int b  = rec/(NS*DD);
  const float a = -expf(Alog[d*NS+n]);
  float hend[8], dA[8];
  #pragma unroll
  for (int j=0;j<8;j++){
    int c = lane*8 + j;
    size_t o = (((size_t)(b*NC+c))*64 + d)*12;
    hend[j] = chunkst[o+n];
    dA[j]   = __expf(a*chunkst[o+NS]);
  }
  // local affine compose over 8 chunks: h -> A*h + Bv
  float A = 1.f, Bv = 0.f;
  #pragma unroll
  for (int j=0;j<8;j++){
    Bv = fmaf(dA[j], Bv, hend[j]);
    A *= dA[j];
  }
  // inclusive wave scan of affine pairs (composition is associative)
  #pragma unroll
  for (int off=1; off<64; off<<=1){
    float Ap = __shfl_up(A,  off, 64);
    float Bp = __shfl_up(Bv, off, 64);
    if (lane >= off){ Bv = fmaf(A, Bp, Bv); A *= Ap; }
  }
  // exclusive prefix for this lane
  float Bex = __shfl_up(Bv, 1, 64);
  if (lane==0) Bex = 0.f;
  // replay: h at chunk start (global h0 = 0 so state = B component)
  float h = Bex;
  #pragma unroll
  for (int j=0;j<8;j++){
    int c = lane*8 + j;
    hin[(((size_t)(b*NC+c))*64 + d)*NS + n] = h;
    h = fmaf(dA[j], h, hend[j]);
  }
}

// ---------------- K5: replay scan with h_in, y, RMSNorm over D, SiLU gating -------
__global__ __launch_bounds__(256,4) void k_scanB(const float* __restrict__ delta,
                                               const float* __restrict__ u,
                                               const float* __restrict__ bc,
                                               const float* __restrict__ Alog,
                                               const float* __restrict__ hin,
                                               const float* __restrict__ Dsv,
                                               const float* __restrict__ rmss,
                                               const float* __restrict__ x,
                                               float* __restrict__ out){
  const int task = blockIdx.x*4 + (threadIdx.x>>6);
  const int d = threadIdx.x & 63;
  const int b = task / NC, c = task % NC;
  float a[NS], h[NS];
  #pragma unroll
  for (int n=0;n<NS;n++) a[n] = -expf(Alog[d*NS+n]);
  size_t ho = ((size_t)task*64 + d)*NS;
  #pragma unroll
  for (int n=0;n<NS;n++) h[n] = hin[ho+n];
  const float Dd = Dsv[d];
  const float rsc = rmss[d];
  const int l0 = c*LC;
  #pragma unroll 2
  for (int l=l0; l<l0+LC; ++l){
    size_t p = (size_t)b*LL + l;
    float de = delta[p*DD+d];
    float uu = u[p*DD+d];
    float du = de*uu;
    float bca[24];
    const float4* q = reinterpret_cast<const float4*>(bc + p*24);
    *reinterpret_cast<float4*>(&bca[0])  = q[0];
    *reinterpret_cast<float4*>(&bca[4])  = q[1];
    *reinterpret_cast<float4*>(&bca[8])  = q[2];
    *reinterpret_cast<float4*>(&bca[12]) = q[3];
    *reinterpret_cast<float4*>(&bca[16]) = q[4];
    *reinterpret_cast<float4*>(&bca[20]) = q[5];
    float y = Dd*uu;
    #pragma unroll
    for (int n=0;n<NS;n++){
      float dA = __expf(a[n]*de);
      h[n] = fmaf(dA, h[n], du*bca[n]);
      y = fmaf(h[n], bca[12+n], y);
    }
    float ss = y*y;
    #pragma unroll
    for (int m=1;m<64;m<<=1) ss += __shfl_xor(ss, m, 64);
    float yn = rsc * rsqrtf(ss*(1.f/64.f) + 1e-5f) * y;
    float z = x[p*DD+d];
    out[p*DD+d] = yn * (z * sigmoidf_(z));
  }
}

extern "C" void kernel_launch(void* const* d_in, const int* in_sizes, int n_in,
                              void* d_out, int out_size, void* d_ws, size_t ws_size,
                              hipStream_t stream) {
  const float* x     = (const float*)d_in[0];
  const float* w     = (const float*)d_in[1];
  const float* gamma = (const float*)d_in[2];
  const float* beta  = (const float*)d_in[3];
  const float* xpw   = (const float*)d_in[4];
  const float* dtw   = (const float*)d_in[5];
  const float* dtb   = (const float*)d_in[6];
  const float* Alog  = (const float*)d_in[7];
  const float* Dsv   = (const float*)d_in[8];
  const float* rmss  = (const float*)d_in[9];
  float* out = (float*)d_out;

  float* f = (float*)d_ws;
  const size_t n_xld = (size_t)NB*LL*DD;       // 4,194,304
  float* xc      = f;                          // conv out, later overwritten by delta
  float* u       = xc + n_xld;
  float* bc      = u  + n_xld;                 // (b,l,24): B[0..10],pad,C[0..10],pad
  float* chunkst = bc + (size_t)NB*LL*24;      // (b,c,d,12)
  float* hin     = chunkst + (size_t)NB*NC*64*12;  // (b,c,d,11)
  float* bn_acc  = hin + (size_t)NB*NC*64*NS;

  hipMemsetAsync(bn_acc, 0, 128*sizeof(float), stream);
  k_conv   <<<NB*(LL/CONV_LT), 256, 0, stream>>>(x, w, xc, bn_acc);
  k_proj   <<<NB*(LL/64), 256, 0, stream>>>(xc, bn_acc, gamma, beta, xpw, dtw, dtb, u, bc);
  k_scanA  <<<(NB*NC)/4, 256, 0, stream>>>(xc, u, bc, Alog, chunkst);
  k_scanMid<<<(NB*DD*NS)/4, 256, 0, stream>>>(chunkst, Alog, hin);
  k_scanB  <<<(NB*NC)/4, 256, 0, stream>>>(xc, u, bc, Alog, hin, Dsv, rmss, x, out);
}